// Round 3
// baseline (1847.124 us; speedup 1.0000x reference)
//
#include <hip/hip_runtime.h>
#include <hip/hip_bf16.h>

// TreeNet: T=512 nodes, B=256 batch, D=256 dim, BF=2 branching.
// Decomposition:
//   K0  stack simulation (int only) -> child lists / worklists
//   K1  H = inputs @ W_in + b            (parallel GEMM, into memory region)
//   K2a G[t] += tanh(H[leaf_child]) @ W_ch[i]   (parallel gather-GEMM, x2 lists)
//   K2b memory[leaf] = tanh(H[leaf])     (parallel elementwise)
//   K3  sequential per-batch chain. R3: LDS-BW fix — child vector enters via
//       1 ds_read_b32/lane, broadcast by v_readlane into v_dot2_f32_f16
//       (w as 64 f16-pairs in VGPRs). Output rows buffered in LDS ring,
//       flushed every 8 steps (amortize vmcnt(0) barrier drain). Next G row
//       prefetched during compute.
//   K4  out[k] = memory[root[k], k]

constexpr int T = 512, B = 256, D = 256;

typedef _Float16 h2 __attribute__((ext_vector_type(2)));

__device__ __forceinline__ float dot2f(h2 a, h2 b, float c) {
#if __has_builtin(__builtin_amdgcn_fdot2)
  return __builtin_amdgcn_fdot2(a, b, c, false);
#else
  return c + (float)a.x * (float)b.x + (float)a.y * (float)b.y;
#endif
}

// ws layout in u32 units
constexpr int WS_CNT  = 0;        // [2] atomic counters for leaf lists
constexpr int WS_ROOT = 16;       // [256]
constexpr int WS_NW   = 272;      // [256]
constexpr int WS_L0   = 1024;     // [131072] leaf-child entries, i=0
constexpr int WS_L1   = WS_L0 + T * B;     // [131072] i=1
constexpr int WS_WORK = WS_L1 + T * B;     // [256*1024] per-k combine worklist

// ---------------- K0: stack simulation ----------------
__global__ __launch_bounds__(256) void k_stack(const int* __restrict__ ar,
                                               unsigned* __restrict__ ws) {
  __shared__ int ar_l[T];
  __shared__ int S[1024];
  __shared__ unsigned lbuf0[T];
  __shared__ unsigned lbuf1[T];
  __shared__ unsigned wbuf[1024];
  __shared__ int cnts[4];
  __shared__ unsigned base0, base1;

  int k = blockIdx.x;
  int tid = threadIdx.x;
  ar_l[tid]       = ar[tid * B + k];
  ar_l[tid + 256] = ar[(tid + 256) * B + k];
  S[tid] = 0; S[tid + 256] = 0; S[tid + 512] = 0; S[tid + 768] = 0;
  __syncthreads();

  if (tid == 0) {
    int ptr = 1;
    int top = 0, next = 0;
    int n0 = 0, n1 = 0, nw = 0;
    for (int t = 0; t < T; t++) {
      int a = ar_l[t];
      int aa = a < 0 ? -a : a;
      unsigned cc[2]; int ncc = 0;
      if (a > 0) {
        int c0 = top;
        if (ar_l[c0] <= 0)
          lbuf0[n0++] = (unsigned)c0 | ((unsigned)t << 9) | ((unsigned)k << 18);
        else
          cc[ncc++] = (unsigned)c0;
        if (a > 1) {
          int c1 = next;
          if (ar_l[c1] <= 0)
            lbuf1[n1++] = (unsigned)c1 | ((unsigned)t << 9) | ((unsigned)k << 18);
          else
            cc[ncc++] = (unsigned)c1 | (1u << 18);
        }
      }
      if (a >= 1) {
        if (ncc == 0) {
          wbuf[nw++] = (unsigned)t | (1u << 19) | (1u << 20);
        } else {
          for (int e = 0; e < ncc; e++) {
            unsigned w = (unsigned)t | ((cc[e] & 511u) << 9) |
                         (((cc[e] >> 18) & 1u) << 18) | (1u << 21);
            if (e == 0) w |= (1u << 19);
            if (e == ncc - 1) w |= (1u << 20);
            wbuf[nw++] = w;
          }
        }
      }
      int pnew = ptr - aa + 1;
      if (a != -1) {
        S[pnew & 1023] = t;
        if (aa == 0)      { next = top; top = t; }
        else if (aa == 1) { top = t; }
        else              { top = t; next = S[(pnew - 1) & 1023]; }
      }
      ptr = pnew;
    }
    cnts[0] = n0; cnts[1] = n1; cnts[2] = nw;
    cnts[3] = S[ptr & 1023];
    base0 = atomicAdd(ws + WS_CNT + 0, (unsigned)n0);
    base1 = atomicAdd(ws + WS_CNT + 1, (unsigned)n1);
  }
  __syncthreads();
  int n0 = cnts[0], n1 = cnts[1], nw = cnts[2];
  for (int i = tid; i < n0; i += 256) ws[WS_L0 + base0 + i] = lbuf0[i];
  for (int i = tid; i < n1; i += 256) ws[WS_L1 + base1 + i] = lbuf1[i];
  for (int i = tid; i < nw; i += 256) ws[WS_WORK + k * 1024 + i] = wbuf[i];
  if (tid == 0) { ws[WS_NW + k] = (unsigned)nw; ws[WS_ROOT + k] = (unsigned)cnts[3]; }
}

// ---------------- K1: H = X @ W_in + b ----------------
__global__ __launch_bounds__(256) void k_gemm_h(const float* __restrict__ X,
                                                const float* __restrict__ W,
                                                const float* __restrict__ bias,
                                                float* __restrict__ Hm) {
  int row0 = blockIdx.x * 64;
  __shared__ float As[16][65];
  __shared__ float Bs[16][256];
  int tid = threadIdx.x;
  int cq = tid & 31, rg = tid >> 5;
  float acc[8][8];
#pragma unroll
  for (int q = 0; q < 8; q++) {
    float bv = bias[cq + 32 * q];
#pragma unroll
    for (int rr = 0; rr < 8; rr++) acc[rr][q] = bv;
  }
  int sr = tid >> 2;
  int skc = (tid & 3) * 4;
  for (int kk = 0; kk < 256; kk += 16) {
    float4 a4 = *(const float4*)&X[(row0 + sr) * 256 + kk + skc];
    As[skc + 0][sr] = a4.x; As[skc + 1][sr] = a4.y;
    As[skc + 2][sr] = a4.z; As[skc + 3][sr] = a4.w;
#pragma unroll
    for (int r = 0; r < 16; r++) Bs[r][tid] = W[(kk + r) * 256 + tid];
    __syncthreads();
#pragma unroll
    for (int kc = 0; kc < 16; kc++) {
      float a[8], bb[8];
#pragma unroll
      for (int rr = 0; rr < 8; rr++) a[rr] = As[kc][rg * 8 + rr];
#pragma unroll
      for (int q = 0; q < 8; q++) bb[q] = Bs[kc][cq + 32 * q];
#pragma unroll
      for (int rr = 0; rr < 8; rr++)
#pragma unroll
        for (int q = 0; q < 8; q++) acc[rr][q] += a[rr] * bb[q];
    }
    __syncthreads();
  }
#pragma unroll
  for (int rr = 0; rr < 8; rr++)
#pragma unroll
    for (int q = 0; q < 8; q++)
      Hm[(row0 + rg * 8 + rr) * 256 + cq + 32 * q] = acc[rr][q];
}

// ---------------- K2a: gather-GEMM of leaf-child contributions ----------------
__global__ __launch_bounds__(256) void k_leafgemm(const float* __restrict__ Hm,
                                                  float* __restrict__ Gm,
                                                  const float* __restrict__ Wch,
                                                  const unsigned* __restrict__ list,
                                                  const unsigned* __restrict__ cntp,
                                                  int which) {
  unsigned cnt = *cntp;
  unsigned tile0 = blockIdx.x * 64;
  if (tile0 >= cnt) return;
  int ne = (int)min(64u, cnt - tile0);
  __shared__ unsigned ent[64];
  __shared__ float As[16][65];
  __shared__ float Bs[16][256];
  int tid = threadIdx.x;
  if (tid < 64) ent[tid] = (tid < ne) ? list[tile0 + tid] : 0u;
  __syncthreads();
  const float* W = Wch + which * (D * D);
  int cq = tid & 31, rg = tid >> 5;
  float acc[8][8];
#pragma unroll
  for (int rr = 0; rr < 8; rr++)
#pragma unroll
    for (int q = 0; q < 8; q++) acc[rr][q] = 0.0f;
  int sr = tid >> 2;
  int skc = (tid & 3) * 4;
  unsigned se = ent[sr];
  int sc = (int)(se & 511u), skb = (int)((se >> 18) & 255u);
  const float* srow = &Hm[((sc << 8) + skb) * 256];
  for (int kk = 0; kk < 256; kk += 16) {
    float4 a4;
    if (sr < ne) a4 = *(const float4*)&srow[kk + skc];
    else { a4.x = a4.y = a4.z = a4.w = 0.0f; }
    As[skc + 0][sr] = tanhf(a4.x); As[skc + 1][sr] = tanhf(a4.y);
    As[skc + 2][sr] = tanhf(a4.z); As[skc + 3][sr] = tanhf(a4.w);
#pragma unroll
    for (int r = 0; r < 16; r++) Bs[r][tid] = W[(kk + r) * 256 + tid];
    __syncthreads();
#pragma unroll
    for (int kc = 0; kc < 16; kc++) {
      float a[8], bb[8];
#pragma unroll
      for (int rr = 0; rr < 8; rr++) a[rr] = As[kc][rg * 8 + rr];
#pragma unroll
      for (int q = 0; q < 8; q++) bb[q] = Bs[kc][cq + 32 * q];
#pragma unroll
      for (int rr = 0; rr < 8; rr++)
#pragma unroll
        for (int q = 0; q < 8; q++) acc[rr][q] += a[rr] * bb[q];
    }
    __syncthreads();
  }
#pragma unroll
  for (int rr = 0; rr < 8; rr++) {
    int e = rg * 8 + rr;
    if (e < ne) {
      unsigned en = ent[e];
      int t = (int)((en >> 9) & 511u), kb = (int)((en >> 18) & 255u);
      float* dst = &Gm[((t << 8) + kb) * 256];
#pragma unroll
      for (int q = 0; q < 8; q++) dst[cq + 32 * q] += acc[rr][q];
    }
  }
}

// ---------------- K2b: tanh leaves in place ----------------
__global__ __launch_bounds__(256) void k_leaftanh(const int* __restrict__ ar,
                                                  float* __restrict__ Mm) {
  int r0 = blockIdx.x * 64;
  __shared__ int lar[64];
  int tid = threadIdx.x;
  if (tid < 64) lar[tid] = ar[r0 + tid];
  __syncthreads();
  for (int r = 0; r < 64; r++) {
    if (lar[r] <= 0) {
      float v = Mm[(r0 + r) * 256 + tid];
      Mm[(r0 + r) * 256 + tid] = tanhf(v);
    }
  }
}

// ---------------- K3: sequential combine chain, one wg per batch ----------------
// 512 threads: j = tid&255 (output column), h = tid>>8 (K-half).
// w: 64 f16-pairs/thread = W_ch[1][h*128 + 2q (+1)][j].
// Per step: 1 ds_read_b32/lane for child pairs, v_readlane broadcast into
// v_dot2_f32_f16. Ring-buffered output stores flushed every 8 steps.
__global__ __launch_bounds__(512) void k_seq(float* __restrict__ Mm,
                                             const float* __restrict__ Wch,
                                             const unsigned* __restrict__ ws) {
  int k = blockIdx.x;
  int tid = threadIdx.x;
  int j = tid & 255, h = tid >> 8, lane = tid & 63;

  __shared__ unsigned wl[1024];       // staged work entries
  __shared__ _Float16 crow16[256];    // child vector, f16
  __shared__ float partial[256];      // h==1 partial sums
  __shared__ float ring[8][256];      // output rows pending flush
  __shared__ int tstore[8];           // t per ring row

  // stage W_ch[1] column j, K-half h, as f16 pairs (64 VGPRs)
  const float* W1 = Wch + D * D;
  int pbase = h << 7;
  h2 w[64];
#pragma unroll 8
  for (int q = 0; q < 64; q++) {
    float f0 = W1[(pbase + 2 * q) * 256 + j];
    float f1 = W1[(pbase + 2 * q + 1) * 256 + j];
    w[q].x = (_Float16)f0; w[q].y = (_Float16)f1;
  }
  int nw = (int)ws[WS_NW + k];
  for (int i = tid; i < nw; i += 512) wl[i] = ws[WS_WORK + k * 1024 + i];
  __syncthreads();

  int cached = -1;
  int m = 0, flushbase = 0;
  float gcur = 0.0f;
  if (nw > 0 && h == 0) {
    int t0 = (int)(wl[0] & 511u);
    gcur = Mm[((t0 << 8) + k) * 256 + j];
  }
  float a0 = 0.f, a1 = 0.f, a2 = 0.f, a3 = 0.f;

  for (int n = 0; n < nw; n++) {
    unsigned e = wl[n];
    int t = (int)(e & 511u), c = (int)((e >> 9) & 511u);
    int wi = (int)((e >> 18) & 1u);
    bool first = (e >> 19) & 1u, last = (e >> 20) & 1u, hasc = (e >> 21) & 1u;
    if (first) { a1 = a2 = a3 = 0.f; a0 = (h == 0) ? gcur : 0.f; }
    // prefetch next entry's G row during compute
    float gnext = 0.0f;
    if (h == 0 && n + 1 < nw) {
      int tn = (int)(wl[n + 1] & 511u);
      gnext = Mm[((tn << 8) + k) * 256 + j];
    }
    if (hasc) {
      if (c != cached) {  // generic path (not taken by this data)
        // flush pending ring rows so child row is visible in global
        int cnt = m - flushbase;
        for (int i = tid; i < cnt * 256; i += 512) {
          int r = flushbase + (i >> 8), col = i & 255;
          Mm[((tstore[r & 7] << 8) + k) * 256 + col] = ring[r & 7][col];
        }
        flushbase = m;
        __syncthreads();
        if (tid < 256) crow16[tid] = (_Float16)Mm[((c << 8) + k) * 256 + tid];
        __syncthreads();
        cached = c;
      }
      if (wi == 1) {  // fast path: register f16 weights + readlane broadcast
        int cpair = ((const int*)crow16)[(h << 6) | lane];
#pragma unroll
        for (int p = 0; p < 64; p++) {
          int cs = __builtin_amdgcn_readlane(cpair, p);
          union { int i; h2 v; } u; u.i = cs;
          if ((p & 3) == 0)      a0 = dot2f(w[p], u.v, a0);
          else if ((p & 3) == 1) a1 = dot2f(w[p], u.v, a1);
          else if ((p & 3) == 2) a2 = dot2f(w[p], u.v, a2);
          else                   a3 = dot2f(w[p], u.v, a3);
        }
      } else {  // rare: stream W_ch[0] from cache
        for (int p = pbase; p < pbase + 128; p++)
          a0 += (float)crow16[p] * Wch[p * 256 + j];
      }
    }
    if (last) {
      if (h == 1) partial[j] = (a0 + a1) + (a2 + a3);
      __syncthreads();
      if (h == 0) {
        float s = (a0 + a1) + (a2 + a3) + partial[j];
        float v = tanhf(s);
        crow16[j] = (_Float16)v;
        ring[m & 7][j] = v;
      }
      if (tid == 0) tstore[m & 7] = t;
      cached = t;
      m++;
      __syncthreads();
      if ((m & 7) == 0) {  // flush 8 completed rows, coalesced
        for (int i = tid; i < 8 * 256; i += 512) {
          int r = (m - 8) + (i >> 8), col = i & 255;
          Mm[((tstore[r & 7] << 8) + k) * 256 + col] = ring[r & 7][col];
        }
        flushbase = m;
      }
    }
    gcur = gnext;
  }
  // final partial flush
  int cnt = m - flushbase;
  for (int i = tid; i < cnt * 256; i += 512) {
    int r = flushbase + (i >> 8), col = i & 255;
    Mm[((tstore[r & 7] << 8) + k) * 256 + col] = ring[r & 7][col];
  }
}

// ---------------- K4: gather roots ----------------
__global__ __launch_bounds__(256) void k_root(const float* __restrict__ Mm,
                                              float* __restrict__ out,
                                              const unsigned* __restrict__ ws) {
  int k = blockIdx.x;
  unsigned r = ws[WS_ROOT + k];
  out[k * 256 + threadIdx.x] = Mm[(((int)r << 8) + k) * 256 + threadIdx.x];
}

extern "C" void kernel_launch(void* const* d_in, const int* in_sizes, int n_in,
                              void* d_out, int out_size, void* d_ws, size_t ws_size,
                              hipStream_t stream) {
  const float* X    = (const float*)d_in[0];
  const int*   AR   = (const int*)d_in[1];
  const float* Win  = (const float*)d_in[2];
  const float* Wch  = (const float*)d_in[3];
  const float* bias = (const float*)d_in[4];
  float* out = (float*)d_out;
  float* Mm  = out + B * D;  // memory region of output doubles as H/G scratch
  unsigned* ws = (unsigned*)d_ws;

  hipMemsetAsync(d_ws, 0, 512, stream);  // zero atomic counters
  k_stack<<<B, 256, 0, stream>>>(AR, ws);
  k_gemm_h<<<(T * B) / 64, 256, 0, stream>>>(X, Win, bias, Mm);
  k_leafgemm<<<(T * B) / 64, 256, 0, stream>>>(Mm, Mm, Wch, ws + WS_L0, ws + WS_CNT + 0, 0);
  k_leafgemm<<<(T * B) / 64, 256, 0, stream>>>(Mm, Mm, Wch, ws + WS_L1, ws + WS_CNT + 1, 1);
  k_leaftanh<<<(T * B) / 64, 256, 0, stream>>>(AR, Mm);
  k_seq<<<B, 512, 0, stream>>>(Mm, Wch, ws);
  k_root<<<B, 256, 0, stream>>>(Mm, out, ws);
}